// Round 1
// baseline (16612.956 us; speedup 1.0000x reference)
//
#include <hip/hip_runtime.h>
#include <cmath>

// Problem constants (fixed by the reference)
#define DD   512
#define HH   1024
#define BB   4
#define SS   4096
#define CHK  64
#define NCHK 64
#define TOK  256   /* BB*CHK tokens per chunk */

static constexpr float ERRSCALE = 2.0f / (float)(TOK * DD);   // 2/131072

__device__ __forceinline__ float sigmoidf_(float v) { return 1.0f / (1.0f + expf(-v)); }
__device__ __forceinline__ float clip1f_(float v) { return fminf(fmaxf(v, -1.0f), 1.0f); }

// ---------------------------------------------------------------------------
// gemm_nt: C[M,N] = A[M,K] * B[N,K]^T   (B row-major [N,K]; optional B = B0+B1)
// MODE 0: plain store
// MODE 1: rearrange store: input row r=b*SS+s -> chunk-major row t*256+b*64+c
// MODE 2: store raw acc to aux2 (pre1) and silu(acc) to C (a1)
// MODE 3: store silu(acc) to C
// MODE 4: C = ERRSCALE * clip(acc - aux[row,col])   (db2)
// MODE 5: scatter store to d_out: chunk row m -> global row b*SS + t*CHK + c
// ---------------------------------------------------------------------------
template<int BM, int BN, int BK, int TM, int TN, int MODE, bool BADD>
__global__ __launch_bounds__(256) void gemm_nt_k(
    const float* __restrict__ A, const float* __restrict__ B0,
    const float* __restrict__ B1, float* __restrict__ C,
    int M, int N, int K,
    const float* __restrict__ aux, float* __restrict__ aux2, int t)
{
    constexpr int NT = (BM / TM) * (BN / TN);
    static_assert(NT == 256, "256 threads");
    constexpr int KQ = BK / 4;

    __shared__ float As[BK][BM + 4];
    __shared__ float Bs[BK][BN + 4];

    const int tid = threadIdx.x;
    const int tx = tid % (BN / TN);
    const int ty = tid / (BN / TN);
    const int m0 = blockIdx.y * BM;
    const int n0 = blockIdx.x * BN;

    float acc[TM][TN];
#pragma unroll
    for (int i = 0; i < TM; ++i)
#pragma unroll
        for (int j = 0; j < TN; ++j) acc[i][j] = 0.0f;

    for (int k0 = 0; k0 < K; k0 += BK) {
        constexpr int AV = BM * BK / 4;
        for (int i = tid; i < AV; i += NT) {
            int m = i / KQ, kq = i % KQ;
            const float4 v = *(const float4*)(A + (size_t)(m0 + m) * K + k0 + kq * 4);
            As[kq * 4 + 0][m] = v.x; As[kq * 4 + 1][m] = v.y;
            As[kq * 4 + 2][m] = v.z; As[kq * 4 + 3][m] = v.w;
        }
        constexpr int BV = BN * BK / 4;
        for (int i = tid; i < BV; i += NT) {
            int n = i / KQ, kq = i % KQ;
            size_t idx = (size_t)(n0 + n) * K + k0 + kq * 4;
            float4 v = *(const float4*)(B0 + idx);
            if (BADD) {
                const float4 w = *(const float4*)(B1 + idx);
                v.x += w.x; v.y += w.y; v.z += w.z; v.w += w.w;
            }
            Bs[kq * 4 + 0][n] = v.x; Bs[kq * 4 + 1][n] = v.y;
            Bs[kq * 4 + 2][n] = v.z; Bs[kq * 4 + 3][n] = v.w;
        }
        __syncthreads();
#pragma unroll
        for (int kk = 0; kk < BK; ++kk) {
            float ar[TM], br[TN];
#pragma unroll
            for (int i = 0; i < TM; ++i) ar[i] = As[kk][ty * TM + i];
#pragma unroll
            for (int j = 0; j < TN; ++j) br[j] = Bs[kk][tx * TN + j];
#pragma unroll
            for (int i = 0; i < TM; ++i)
#pragma unroll
                for (int j = 0; j < TN; ++j)
                    acc[i][j] = fmaf(ar[i], br[j], acc[i][j]);
        }
        __syncthreads();
    }

#pragma unroll
    for (int i = 0; i < TM; ++i) {
        const int row = m0 + ty * TM + i;
#pragma unroll
        for (int j = 0; j < TN; ++j) {
            const int col = n0 + tx * TN + j;
            const float v = acc[i][j];
            if (MODE == 0) {
                C[(size_t)row * N + col] = v;
            } else if (MODE == 1) {
                const int b = row >> 12, s = row & (SS - 1);
                const int tt = s >> 6, c = s & (CHK - 1);
                const int orow = (tt << 8) | (b << 6) | c;
                C[(size_t)orow * N + col] = v;
            } else if (MODE == 2) {
                const float sg = sigmoidf_(v);
                aux2[(size_t)row * N + col] = v;
                C[(size_t)row * N + col] = v * sg;
            } else if (MODE == 3) {
                const float sg = sigmoidf_(v);
                C[(size_t)row * N + col] = v * sg;
            } else if (MODE == 4) {
                float e = v - aux[(size_t)row * N + col];
                e = clip1f_(e);
                C[(size_t)row * N + col] = e * ERRSCALE;
            } else if (MODE == 5) {
                const int b = row >> 6, c = row & (CHK - 1);
                C[((size_t)b * SS + (size_t)t * CHK + c) * DD + col] = v;
            }
        }
    }
}

// ---------------------------------------------------------------------------
// gemm_nn with silu'-epilogue: C[M,N] = (A[M,K] * (B0+B1)[K,N]) * silu'(pre[M,N])
// ---------------------------------------------------------------------------
template<int BM, int BN, int BK, int TM, int TN>
__global__ __launch_bounds__(256) void gemm_nn_dsilu_k(
    const float* __restrict__ A, const float* __restrict__ B0,
    const float* __restrict__ B1, float* __restrict__ C,
    int M, int N, int K, const float* __restrict__ pre)
{
    constexpr int NT = (BM / TM) * (BN / TN);
    static_assert(NT == 256, "256 threads");
    constexpr int KQ = BK / 4;

    __shared__ float As[BK][BM + 4];
    __shared__ float Bs[BK][BN + 4];

    const int tid = threadIdx.x;
    const int tx = tid % (BN / TN);
    const int ty = tid / (BN / TN);
    const int m0 = blockIdx.y * BM;
    const int n0 = blockIdx.x * BN;

    float acc[TM][TN];
#pragma unroll
    for (int i = 0; i < TM; ++i)
#pragma unroll
        for (int j = 0; j < TN; ++j) acc[i][j] = 0.0f;

    for (int k0 = 0; k0 < K; k0 += BK) {
        constexpr int AV = BM * BK / 4;
        for (int i = tid; i < AV; i += NT) {
            int m = i / KQ, kq = i % KQ;
            const float4 v = *(const float4*)(A + (size_t)(m0 + m) * K + k0 + kq * 4);
            As[kq * 4 + 0][m] = v.x; As[kq * 4 + 1][m] = v.y;
            As[kq * 4 + 2][m] = v.z; As[kq * 4 + 3][m] = v.w;
        }
        constexpr int BV = BK * BN / 4;
        for (int i = tid; i < BV; i += NT) {
            int kk = i / (BN / 4), nq = i % (BN / 4);
            size_t idx = (size_t)(k0 + kk) * N + n0 + nq * 4;
            float4 v = *(const float4*)(B0 + idx);
            const float4 w = *(const float4*)(B1 + idx);
            v.x += w.x; v.y += w.y; v.z += w.z; v.w += w.w;
            Bs[kk][nq * 4 + 0] = v.x; Bs[kk][nq * 4 + 1] = v.y;
            Bs[kk][nq * 4 + 2] = v.z; Bs[kk][nq * 4 + 3] = v.w;
        }
        __syncthreads();
#pragma unroll
        for (int kk = 0; kk < BK; ++kk) {
            float ar[TM], br[TN];
#pragma unroll
            for (int i = 0; i < TM; ++i) ar[i] = As[kk][ty * TM + i];
#pragma unroll
            for (int j = 0; j < TN; ++j) br[j] = Bs[kk][tx * TN + j];
#pragma unroll
            for (int i = 0; i < TM; ++i)
#pragma unroll
                for (int j = 0; j < TN; ++j)
                    acc[i][j] = fmaf(ar[i], br[j], acc[i][j]);
        }
        __syncthreads();
    }

#pragma unroll
    for (int i = 0; i < TM; ++i) {
        const int row = m0 + ty * TM + i;
#pragma unroll
        for (int j = 0; j < TN; ++j) {
            const int col = n0 + tx * TN + j;
            const float p = pre[(size_t)row * N + col];
            const float s = sigmoidf_(p);
            const float d = s * (1.0f + p * (1.0f - s));
            C[(size_t)row * N + col] = acc[i][j] * d;
        }
    }
}

// ---------------------------------------------------------------------------
// gemm_tn with clip + momentum/decay state update:
//   g[i,j] = clip( sum_m A[m,i] * B[m,j] )
//   Mst[i,j] = eta*Mst[i,j] - lr*g ;  Dst[i,j] = (1-dec)*Dst[i,j] + Mst[i,j]
// A: [KM, I] row-major, B: [KM, J] row-major, state: [I, J] row-major
// ---------------------------------------------------------------------------
template<int BI, int BJ, int BK, int TI, int TJ>
__global__ __launch_bounds__(256) void gemm_tn_update_k(
    const float* __restrict__ A, const float* __restrict__ B,
    float* __restrict__ Mst, float* __restrict__ Dst,
    int I, int J, int KM,
    const float* __restrict__ gates, int t)
{
    constexpr int NT = (BI / TI) * (BJ / TJ);
    static_assert(NT == 256, "256 threads");

    __shared__ float As[BK][BI + 4];
    __shared__ float Bs[BK][BJ + 4];

    const int tid = threadIdx.x;
    const int tx = tid % (BJ / TJ);
    const int ty = tid / (BJ / TJ);
    const int i0 = blockIdx.y * BI;
    const int j0 = blockIdx.x * BJ;

    float acc[TI][TJ];
#pragma unroll
    for (int i = 0; i < TI; ++i)
#pragma unroll
        for (int j = 0; j < TJ; ++j) acc[i][j] = 0.0f;

    for (int k0 = 0; k0 < KM; k0 += BK) {
        constexpr int AV = BK * BI / 4;
        for (int i = tid; i < AV; i += NT) {
            int mk = i / (BI / 4), iq = i % (BI / 4);
            const float4 v = *(const float4*)(A + (size_t)(k0 + mk) * I + i0 + iq * 4);
            As[mk][iq * 4 + 0] = v.x; As[mk][iq * 4 + 1] = v.y;
            As[mk][iq * 4 + 2] = v.z; As[mk][iq * 4 + 3] = v.w;
        }
        constexpr int BV = BK * BJ / 4;
        for (int i = tid; i < BV; i += NT) {
            int mk = i / (BJ / 4), jq = i % (BJ / 4);
            const float4 v = *(const float4*)(B + (size_t)(k0 + mk) * J + j0 + jq * 4);
            Bs[mk][jq * 4 + 0] = v.x; Bs[mk][jq * 4 + 1] = v.y;
            Bs[mk][jq * 4 + 2] = v.z; Bs[mk][jq * 4 + 3] = v.w;
        }
        __syncthreads();
#pragma unroll
        for (int kk = 0; kk < BK; ++kk) {
            float ar[TI], br[TJ];
#pragma unroll
            for (int i = 0; i < TI; ++i) ar[i] = As[kk][ty * TI + i];
#pragma unroll
            for (int j = 0; j < TJ; ++j) br[j] = Bs[kk][tx * TJ + j];
#pragma unroll
            for (int i = 0; i < TI; ++i)
#pragma unroll
                for (int j = 0; j < TJ; ++j)
                    acc[i][j] = fmaf(ar[i], br[j], acc[i][j]);
        }
        __syncthreads();
    }

    const float dec = gates[t];
    const float lrv = gates[NCHK + t];
    const float eta = gates[2 * NCHK + t];

#pragma unroll
    for (int i = 0; i < TI; ++i) {
        const int ri = i0 + ty * TI + i;
#pragma unroll
        for (int j = 0; j < TJ; ++j) {
            const int rj = j0 + tx * TJ + j;
            const float g = clip1f_(acc[i][j]);
            const size_t idx = (size_t)ri * J + rj;
            const float mn = eta * Mst[idx] - lrv * g;
            Mst[idx] = mn;
            Dst[idx] = (1.0f - dec) * Dst[idx] + mn;
        }
    }
}

// ---------------------------------------------------------------------------
// l2norm rows in place; blockIdx.y selects kc (0) or qc (1). One wave per row.
// ---------------------------------------------------------------------------
__global__ __launch_bounds__(256) void l2norm_k(float* __restrict__ kc, float* __restrict__ qc)
{
    float* buf = (blockIdx.y == 0) ? kc : qc;
    const int row = blockIdx.x * 4 + (threadIdx.x >> 6);
    const int lane = threadIdx.x & 63;
    float4* p = (float4*)(buf + (size_t)row * DD);
    float4 v0 = p[lane];
    float4 v1 = p[lane + 64];
    float ss = v0.x * v0.x + v0.y * v0.y + v0.z * v0.z + v0.w * v0.w
             + v1.x * v1.x + v1.y * v1.y + v1.z * v1.z + v1.w * v1.w;
#pragma unroll
    for (int m = 32; m >= 1; m >>= 1) ss += __shfl_xor(ss, m);
    const float sc = 1.0f / (sqrtf(ss) + 1e-8f);
    v0.x *= sc; v0.y *= sc; v0.z *= sc; v0.w *= sc;
    v1.x *= sc; v1.y *= sc; v1.z *= sc; v1.w *= sc;
    p[lane] = v0;
    p[lane + 64] = v1;
}

// ---------------------------------------------------------------------------
// Per-token gate sigmoids. One wave per token (chunk-major index).
// gtok layout: [3][16384]
// ---------------------------------------------------------------------------
__global__ __launch_bounds__(256) void gates_tok_k(
    const float* __restrict__ x,
    const float* __restrict__ gdw, const float* __restrict__ gdb,
    const float* __restrict__ glw, const float* __restrict__ glb,
    const float* __restrict__ gmw, const float* __restrict__ gmb,
    float* __restrict__ gtok)
{
    const int wid = (blockIdx.x * 256 + threadIdx.x) >> 6;  // chunk-major token id
    const int lane = threadIdx.x & 63;
    const int t = wid >> 8;
    const int rem = wid & 255;
    const int b = rem >> 6;
    const int c = rem & 63;
    const float* xr = x + ((size_t)b * SS + (size_t)t * CHK + c) * DD;
    float s0 = 0.0f, s1 = 0.0f, s2 = 0.0f;
#pragma unroll
    for (int jj = 0; jj < DD / 64; ++jj) {
        const int j = lane + jj * 64;
        const float xv = xr[j];
        s0 = fmaf(xv, gdw[j], s0);
        s1 = fmaf(xv, glw[j], s1);
        s2 = fmaf(xv, gmw[j], s2);
    }
#pragma unroll
    for (int m = 32; m >= 1; m >>= 1) {
        s0 += __shfl_xor(s0, m);
        s1 += __shfl_xor(s1, m);
        s2 += __shfl_xor(s2, m);
    }
    if (lane == 0) {
        gtok[0 * (NCHK * TOK) + wid] = sigmoidf_(s0 + gdb[0]);
        gtok[1 * (NCHK * TOK) + wid] = sigmoidf_(s1 + glb[0]);
        gtok[2 * (NCHK * TOK) + wid] = sigmoidf_(s2 + gmb[0]);
    }
}

// Deterministic per-chunk mean of the 256 token gates. gates layout: [3][64]
__global__ __launch_bounds__(256) void gates_red_k(
    const float* __restrict__ gtok, float* __restrict__ gates)
{
    __shared__ float sm[256];
    const int t = blockIdx.x;
    for (int g = 0; g < 3; ++g) {
        sm[threadIdx.x] = gtok[g * (NCHK * TOK) + t * TOK + threadIdx.x];
        __syncthreads();
        for (int s = 128; s >= 1; s >>= 1) {
            if (threadIdx.x < s) sm[threadIdx.x] += sm[threadIdx.x + s];
            __syncthreads();
        }
        if (threadIdx.x == 0) gates[g * NCHK + t] = sm[0] * (1.0f / 256.0f);
        __syncthreads();
    }
}

// ---------------------------------------------------------------------------
extern "C" void kernel_launch(void* const* d_in, const int* in_sizes, int n_in,
                              void* d_out, int out_size, void* d_ws, size_t ws_size,
                              hipStream_t stream)
{
    const float* x    = (const float*)d_in[0];
    const float* Wk   = (const float*)d_in[1];
    const float* Wv   = (const float*)d_in[2];
    const float* Wq   = (const float*)d_in[3];
    const float* Wout = (const float*)d_in[4];
    const float* Wm1  = (const float*)d_in[5];
    const float* Wm2  = (const float*)d_in[6];
    const float* gdw  = (const float*)d_in[7];
    const float* gdb  = (const float*)d_in[8];
    const float* glw  = (const float*)d_in[9];
    const float* glb  = (const float*)d_in[10];
    const float* gmw  = (const float*)d_in[11];
    const float* gmb  = (const float*)d_in[12];
    float* out = (float*)d_out;

    float* ws = (float*)d_ws;
    size_t off = 0;
    auto alloc = [&](size_t n) { float* p = ws + off; off += n; return p; };
    float* kc    = alloc((size_t)NCHK * TOK * DD);   // [64,256,512] chunk-major
    float* vc    = alloc((size_t)NCHK * TOK * DD);
    float* qc    = alloc((size_t)NCHK * TOK * DD);
    float* d1    = alloc((size_t)HH * DD);           // state (contiguous block of 4)
    float* d2    = alloc((size_t)HH * DD);
    float* m1    = alloc((size_t)HH * DD);
    float* m2    = alloc((size_t)HH * DD);
    float* pre1  = alloc((size_t)TOK * HH);
    float* a1    = alloc((size_t)TOK * HH);
    float* db2   = alloc((size_t)TOK * DD);
    float* db1   = alloc((size_t)TOK * HH);
    float* hb    = alloc((size_t)TOK * HH);
    float* yc    = alloc((size_t)TOK * DD);
    float* gtok  = alloc((size_t)3 * NCHK * TOK);
    float* gates = alloc((size_t)3 * NCHK);

    // zero the scan state (d1,d2,m1,m2 are contiguous)
    hipMemsetAsync(d1, 0, (size_t)4 * HH * DD * sizeof(float), stream);

    const dim3 blk(256);
    const int M = BB * SS;  // 16384

    // k_pre, v, q_pre with chunk-major rearrange epilogue
    gemm_nt_k<64, 64, 16, 4, 4, 1, false>
        <<<dim3(DD / 64, M / 64), blk, 0, stream>>>(x, Wk, nullptr, kc, M, DD, DD, nullptr, nullptr, 0);
    gemm_nt_k<64, 64, 16, 4, 4, 1, false>
        <<<dim3(DD / 64, M / 64), blk, 0, stream>>>(x, Wv, nullptr, vc, M, DD, DD, nullptr, nullptr, 0);
    gemm_nt_k<64, 64, 16, 4, 4, 1, false>
        <<<dim3(DD / 64, M / 64), blk, 0, stream>>>(x, Wq, nullptr, qc, M, DD, DD, nullptr, nullptr, 0);

    l2norm_k<<<dim3(M / 4, 2), blk, 0, stream>>>(kc, qc);

    gates_tok_k<<<dim3(M / 4), blk, 0, stream>>>(x, gdw, gdb, glw, glb, gmw, gmb, gtok);
    gates_red_k<<<dim3(NCHK), blk, 0, stream>>>(gtok, gates);

    for (int t = 0; t < NCHK; ++t) {
        const float* kt = kc + (size_t)t * TOK * DD;
        const float* vt = vc + (size_t)t * TOK * DD;
        const float* qt = qc + (size_t)t * TOK * DD;

        // S1: pre1 = kt @ (Wm1+d1)^T ; a1 = silu(pre1)        [256,1024]
        gemm_nt_k<32, 64, 16, 2, 4, 2, true>
            <<<dim3(HH / 64, TOK / 32), blk, 0, stream>>>(kt, Wm1, d1, a1, TOK, HH, DD, nullptr, pre1, 0);
        // S2: db2 = ERRSCALE*clip(a1 @ (Wm2+d2)^T - vt)       [256,512]
        gemm_nt_k<32, 64, 16, 2, 4, 4, true>
            <<<dim3(DD / 64, TOK / 32), blk, 0, stream>>>(a1, Wm2, d2, db2, TOK, DD, HH, vt, nullptr, 0);
        // S3: db1 = (db2 @ (Wm2+d2)) * silu'(pre1)            [256,1024]
        gemm_nn_dsilu_k<32, 64, 16, 2, 4>
            <<<dim3(HH / 64, TOK / 32), blk, 0, stream>>>(db2, Wm2, d2, db1, TOK, HH, DD, pre1);
        // S4: g1 = clip(db1^T @ kt); m1,d1 update             [1024,512]
        gemm_tn_update_k<32, 64, 16, 2, 4>
            <<<dim3(DD / 64, HH / 32), blk, 0, stream>>>(db1, kt, m1, d1, HH, DD, TOK, gates, t);
        // S5: g2 = clip(db2^T @ a1); m2,d2 update             [512,1024]
        gemm_tn_update_k<32, 64, 16, 2, 4>
            <<<dim3(HH / 64, DD / 32), blk, 0, stream>>>(db2, a1, m2, d2, DD, HH, TOK, gates, t);
        // S6: h = silu(qt @ (Wm1+d1_new)^T)                   [256,1024]
        gemm_nt_k<32, 64, 16, 2, 4, 3, true>
            <<<dim3(HH / 64, TOK / 32), blk, 0, stream>>>(qt, Wm1, d1, hb, TOK, HH, DD, nullptr, nullptr, 0);
        // S7: yc = h @ (Wm2+d2_new)^T                         [256,512]
        gemm_nt_k<32, 64, 16, 2, 4, 0, true>
            <<<dim3(DD / 64, TOK / 32), blk, 0, stream>>>(hb, Wm2, d2, yc, TOK, DD, HH, nullptr, nullptr, 0);
        // S8: out_chunk = yc @ Wout^T scattered into d_out    [256,512]
        gemm_nt_k<32, 64, 16, 2, 4, 5, false>
            <<<dim3(DD / 64, TOK / 32), blk, 0, stream>>>(yc, Wout, nullptr, out, TOK, DD, DD, nullptr, nullptr, t);
    }
}

// Round 2
// 5506.470 us; speedup vs baseline: 3.0170x; 3.0170x over previous
//
#include <hip/hip_runtime.h>
#include <cmath>

#define DD   512
#define HH   1024
#define BB   4
#define SS   4096
#define CHK  64
#define NCHK 64
#define TOK  256
#define SA   72   /* padded LDS row stride in bf16 elements (144B, 16B-aligned) */

static constexpr float ERRSCALE = 2.0f / (float)(TOK * DD);

typedef __attribute__((ext_vector_type(8))) short bf16x8;
typedef __attribute__((ext_vector_type(4))) float f32x4;

__device__ __forceinline__ float sigmoidf_(float v) { return 1.0f / (1.0f + expf(-v)); }
__device__ __forceinline__ float clip1f_(float v) { return fminf(fmaxf(v, -1.0f), 1.0f); }

// f32 -> bf16 round-to-nearest-even (finite inputs)
__device__ __forceinline__ ushort f2b(float f) {
    union { float f; unsigned u; } v; v.f = f;
    return (ushort)((v.u + 0x7fffu + ((v.u >> 16) & 1u)) >> 16);
}
__device__ __forceinline__ float b2f(ushort u) {
    union { unsigned u; float f; } v; v.u = ((unsigned)u) << 16;
    return v.f;
}

// ---------------------------------------------------------------------------
// LDS staging. Canonical LDS layout: S[row][k] with row stride SA (padded).
// stage_n: global G is [rows, K] row-major (k contiguous)  -> direct 16B copies
// stage_t: global G is [K, rows] row-major (row contiguous) -> LDS transpose
// ---------------------------------------------------------------------------
__device__ __forceinline__ void stage_n(const ushort* __restrict__ G, int ld,
                                        int r0, int k0, ushort* S, int tid) {
#pragma unroll
    for (int p = 0; p < 2; ++p) {
        const int c = tid + p * 256;
        const int r = c >> 3, o = c & 7;
        *(float4*)(S + r * SA + o * 8) =
            *(const float4*)(G + (size_t)(r0 + r) * ld + k0 + o * 8);
    }
}
__device__ __forceinline__ void stage_t(const ushort* __restrict__ G, int ld,
                                        int c0, int k0, ushort* S, int tid) {
    const int kr = tid & 63;
    const int mo0 = (tid >> 6) * 2;
#pragma unroll
    for (int p = 0; p < 2; ++p) {
        const int mo = (mo0 + p) * 8;
        const float4 v = *(const float4*)(G + (size_t)(k0 + kr) * ld + c0 + mo);
        ushort u[8];
        __builtin_memcpy(u, &v, 16);
#pragma unroll
        for (int j = 0; j < 8; ++j) S[(mo + j) * SA + kr] = u[j];
    }
}

// ---------------------------------------------------------------------------
// 64x64 block tile MFMA core, 4 waves of 32x32, K in steps of 64.
// A logical [M,K], B logical [N,K]; ta/tb: global layout transposed ([K,M]).
// ---------------------------------------------------------------------------
__device__ __forceinline__ void gemm_core(
    const ushort* __restrict__ A, int lda, bool ta,
    const ushort* __restrict__ B, int ldb, bool tb,
    int K, int m0, int n0, ushort* As, ushort* Bs, f32x4 acc[2][2])
{
    const int tid = threadIdx.x;
    const int lane = tid & 63;
    const int w = tid >> 6;
    const int wr = (w >> 1) * 32, wc = (w & 1) * 32;
    const int lr = lane & 15, lg = lane >> 4;

    for (int k0 = 0; k0 < K; k0 += 64) {
        if (ta) stage_t(A, lda, m0, k0, As, tid); else stage_n(A, lda, m0, k0, As, tid);
        if (tb) stage_t(B, ldb, n0, k0, Bs, tid); else stage_n(B, ldb, n0, k0, Bs, tid);
        __syncthreads();
#pragma unroll
        for (int ks = 0; ks < 2; ++ks) {
            bf16x8 af[2], bfr[2];
#pragma unroll
            for (int mi = 0; mi < 2; ++mi)
                af[mi] = *(const bf16x8*)(As + (wr + mi * 16 + lr) * SA + ks * 32 + lg * 8);
#pragma unroll
            for (int ni = 0; ni < 2; ++ni)
                bfr[ni] = *(const bf16x8*)(Bs + (wc + ni * 16 + lr) * SA + ks * 32 + lg * 8);
#pragma unroll
            for (int mi = 0; mi < 2; ++mi)
#pragma unroll
                for (int ni = 0; ni < 2; ++ni)
                    acc[mi][ni] = __builtin_amdgcn_mfma_f32_16x16x32_bf16(
                        af[mi], bfr[ni], acc[mi][ni], 0, 0, 0);
        }
        __syncthreads();
    }
}

// Epilogue iterator: calls f(row, col, val). C/D layout: col=lane&15, row=(lane>>4)*4+reg.
template<typename F>
__device__ __forceinline__ void epilogue(int m0, int n0, const f32x4 acc[2][2], F&& f) {
    const int lane = threadIdx.x & 63, w = threadIdx.x >> 6;
    const int wr = (w >> 1) * 32, wc = (w & 1) * 32;
    const int lr = lane & 15, lg = lane >> 4;
#pragma unroll
    for (int mi = 0; mi < 2; ++mi)
#pragma unroll
        for (int ni = 0; ni < 2; ++ni)
#pragma unroll
            for (int r = 0; r < 4; ++r)
                f(m0 + wr + mi * 16 + lg * 4 + r, n0 + wc + ni * 16 + lr, acc[mi][ni][r]);
}

__device__ __forceinline__ void zacc(f32x4 acc[2][2]) {
#pragma unroll
    for (int i = 0; i < 2; ++i)
#pragma unroll
        for (int j = 0; j < 2; ++j) acc[i][j] = 0.0f;
}

// ---------------------------------------------------------------------------
// f32 -> bf16 conversion (vectorized by 4)
// ---------------------------------------------------------------------------
__global__ __launch_bounds__(256) void conv_k(const float* __restrict__ s,
                                              ushort* __restrict__ d, int n4) {
    const int i = blockIdx.x * 256 + threadIdx.x;
    if (i < n4) {
        const float4 v = ((const float4*)s)[i];
        ushort4 o;
        o.x = f2b(v.x); o.y = f2b(v.y); o.z = f2b(v.z); o.w = f2b(v.w);
        ((ushort4*)d)[i] = o;
    }
}

// ---------------------------------------------------------------------------
// Projection GEMM [16384,512] = xb @ W^T, epilogue rearranges rows to
// chunk-major (t*256 + b*64 + c). OM=0: f32 store, OM=1: bf16 store.
// ---------------------------------------------------------------------------
template<int OM>
__global__ __launch_bounds__(256) void proj_k(const ushort* __restrict__ xb,
                                              const ushort* __restrict__ Wb,
                                              float* __restrict__ df,
                                              ushort* __restrict__ db) {
    __shared__ ushort As[64 * SA], Bs[64 * SA];
    f32x4 acc[2][2]; zacc(acc);
    const int m0 = blockIdx.y * 64, n0 = blockIdx.x * 64;
    gemm_core(xb, DD, false, Wb, DD, false, DD, m0, n0, As, Bs, acc);
    epilogue(m0, n0, acc, [&](int row, int col, float val) {
        const int b = row >> 12, s = row & (SS - 1);
        const int t = s >> 6, c = s & 63;
        const size_t orow = (size_t)((t << 8) | (b << 6) | c);
        if (OM == 0) df[orow * DD + col] = val;
        else         db[orow * DD + col] = f2b(val);
    });
}

// l2-normalize rows of kpre/qpre (f32, chunk-major) -> bf16 ktb/qtb
__global__ __launch_bounds__(256) void l2n_k(const float* __restrict__ kp,
                                             const float* __restrict__ qp,
                                             ushort* __restrict__ kb,
                                             ushort* __restrict__ qb) {
    const float* src = blockIdx.y ? qp : kp;
    ushort* dst = blockIdx.y ? qb : kb;
    const int row = blockIdx.x * 4 + (threadIdx.x >> 6);
    const int lane = threadIdx.x & 63;
    const float4* p = (const float4*)(src + (size_t)row * DD);
    float4 v0 = p[lane], v1 = p[lane + 64];
    float ss = v0.x * v0.x + v0.y * v0.y + v0.z * v0.z + v0.w * v0.w
             + v1.x * v1.x + v1.y * v1.y + v1.z * v1.z + v1.w * v1.w;
#pragma unroll
    for (int m = 32; m >= 1; m >>= 1) ss += __shfl_xor(ss, m);
    const float sc = 1.0f / (sqrtf(ss) + 1e-8f);
    ushort4 o0, o1;
    o0.x = f2b(v0.x * sc); o0.y = f2b(v0.y * sc); o0.z = f2b(v0.z * sc); o0.w = f2b(v0.w * sc);
    o1.x = f2b(v1.x * sc); o1.y = f2b(v1.y * sc); o1.z = f2b(v1.z * sc); o1.w = f2b(v1.w * sc);
    *(ushort4*)(dst + (size_t)row * DD + lane * 4) = o0;
    *(ushort4*)(dst + (size_t)row * DD + 256 + lane * 4) = o1;
}

// ---------------------------------------------------------------------------
// Gates (f32, unchanged from round 1)
// ---------------------------------------------------------------------------
__global__ __launch_bounds__(256) void gates_tok_k(
    const float* __restrict__ x,
    const float* __restrict__ gdw, const float* __restrict__ gdb,
    const float* __restrict__ glw, const float* __restrict__ glb,
    const float* __restrict__ gmw, const float* __restrict__ gmb,
    float* __restrict__ gtok)
{
    const int wid = (blockIdx.x * 256 + threadIdx.x) >> 6;
    const int lane = threadIdx.x & 63;
    const int t = wid >> 8;
    const int rem = wid & 255;
    const int b = rem >> 6;
    const int c = rem & 63;
    const float* xr = x + ((size_t)b * SS + (size_t)t * CHK + c) * DD;
    float s0 = 0.0f, s1 = 0.0f, s2 = 0.0f;
#pragma unroll
    for (int jj = 0; jj < DD / 64; ++jj) {
        const int j = lane + jj * 64;
        const float xv = xr[j];
        s0 = fmaf(xv, gdw[j], s0);
        s1 = fmaf(xv, glw[j], s1);
        s2 = fmaf(xv, gmw[j], s2);
    }
#pragma unroll
    for (int m = 32; m >= 1; m >>= 1) {
        s0 += __shfl_xor(s0, m);
        s1 += __shfl_xor(s1, m);
        s2 += __shfl_xor(s2, m);
    }
    if (lane == 0) {
        gtok[0 * (NCHK * TOK) + wid] = sigmoidf_(s0 + gdb[0]);
        gtok[1 * (NCHK * TOK) + wid] = sigmoidf_(s1 + glb[0]);
        gtok[2 * (NCHK * TOK) + wid] = sigmoidf_(s2 + gmb[0]);
    }
}

__global__ __launch_bounds__(256) void gates_red_k(
    const float* __restrict__ gtok, float* __restrict__ gates)
{
    __shared__ float sm[256];
    const int t = blockIdx.x;
    for (int g = 0; g < 3; ++g) {
        sm[threadIdx.x] = gtok[g * (NCHK * TOK) + t * TOK + threadIdx.x];
        __syncthreads();
        for (int s = 128; s >= 1; s >>= 1) {
            if (threadIdx.x < s) sm[threadIdx.x] += sm[threadIdx.x + s];
            __syncthreads();
        }
        if (threadIdx.x == 0) gates[g * NCHK + t] = sm[0] * (1.0f / 256.0f);
        __syncthreads();
    }
}

// ---------------------------------------------------------------------------
// Scan step kernels
// ---------------------------------------------------------------------------
// S1: pre1 = kt @ W1e^T ; a1b = bf16(silu(pre1)) ; ds1 = silu'(pre1) f32
__global__ __launch_bounds__(256) void s1_k(const ushort* __restrict__ kt,
                                            const ushort* __restrict__ W1eb,
                                            ushort* __restrict__ a1b,
                                            float* __restrict__ ds1) {
    __shared__ ushort As[64 * SA], Bs[64 * SA];
    f32x4 acc[2][2]; zacc(acc);
    const int m0 = blockIdx.y * 64, n0 = blockIdx.x * 64;
    gemm_core(kt, DD, false, W1eb, DD, false, DD, m0, n0, As, Bs, acc);
    epilogue(m0, n0, acc, [&](int row, int col, float val) {
        const size_t idx = (size_t)row * HH + col;
        const float sg = sigmoidf_(val);
        a1b[idx] = f2b(val * sg);
        ds1[idx] = sg * (1.0f + val * (1.0f - sg));
    });
}

// S2: db2b = bf16(ERRSCALE * clip(a1 @ W2e^T - v))
__global__ __launch_bounds__(256) void s2_k(const ushort* __restrict__ a1b,
                                            const ushort* __restrict__ W2eb,
                                            const ushort* __restrict__ vt,
                                            ushort* __restrict__ db2b) {
    __shared__ ushort As[64 * SA], Bs[64 * SA];
    f32x4 acc[2][2]; zacc(acc);
    const int m0 = blockIdx.y * 64, n0 = blockIdx.x * 64;
    gemm_core(a1b, HH, false, W2eb, HH, false, HH, m0, n0, As, Bs, acc);
    epilogue(m0, n0, acc, [&](int row, int col, float val) {
        const size_t idx = (size_t)row * DD + col;
        const float e = clip1f_(val - b2f(vt[idx]));
        db2b[idx] = f2b(e * ERRSCALE);
    });
}

// S3: db1b = bf16((db2 @ W2e) * ds1)   (B transposed layout: W2eb is [D,H])
__global__ __launch_bounds__(256) void s3_k(const ushort* __restrict__ db2b,
                                            const ushort* __restrict__ W2eb,
                                            const float* __restrict__ ds1,
                                            ushort* __restrict__ db1b) {
    __shared__ ushort As[64 * SA], Bs[64 * SA];
    f32x4 acc[2][2]; zacc(acc);
    const int m0 = blockIdx.y * 64, n0 = blockIdx.x * 64;
    gemm_core(db2b, DD, false, W2eb, HH, true, DD, m0, n0, As, Bs, acc);
    epilogue(m0, n0, acc, [&](int row, int col, float val) {
        const size_t idx = (size_t)row * HH + col;
        db1b[idx] = f2b(val * ds1[idx]);
    });
}

// S4+S5 merged: gradient GEMMs (both fully transposed) + state update +
// effective-weight bf16 refresh. Blocks [0,128): g1/H x D; [128,256): g2/D x H.
__global__ __launch_bounds__(256) void s45_k(
    const ushort* __restrict__ db1b, const ushort* __restrict__ kt,
    const ushort* __restrict__ db2b, const ushort* __restrict__ a1b,
    float* __restrict__ m1, float* __restrict__ d1,
    const float* __restrict__ Wm1, ushort* __restrict__ W1eb,
    float* __restrict__ m2, float* __restrict__ d2,
    const float* __restrict__ Wm2, ushort* __restrict__ W2eb,
    const float* __restrict__ gates, int t)
{
    __shared__ ushort As[64 * SA], Bs[64 * SA];
    f32x4 acc[2][2]; zacc(acc);
    const float dec = gates[t], lrg = gates[NCHK + t], eta = gates[2 * NCHK + t];
    const int bid = blockIdx.x;
    if (bid < 128) {
        const int m0 = (bid >> 3) * 64, n0 = (bid & 7) * 64;
        gemm_core(db1b, HH, true, kt, DD, true, TOK, m0, n0, As, Bs, acc);
        epilogue(m0, n0, acc, [&](int row, int col, float val) {
            const size_t idx = (size_t)row * DD + col;
            const float g = clip1f_(val);
            const float mn = eta * m1[idx] - lrg * g;
            m1[idx] = mn;
            const float dn = (1.0f - dec) * d1[idx] + mn;
            d1[idx] = dn;
            W1eb[idx] = f2b(Wm1[idx] + dn);
        });
    } else {
        const int b2 = bid - 128;
        const int m0 = (b2 >> 4) * 64, n0 = (b2 & 15) * 64;
        gemm_core(db2b, DD, true, a1b, HH, true, TOK, m0, n0, As, Bs, acc);
        epilogue(m0, n0, acc, [&](int row, int col, float val) {
            const size_t idx = (size_t)row * HH + col;
            const float g = clip1f_(val);
            const float mn = eta * m2[idx] - lrg * g;
            m2[idx] = mn;
            const float dn = (1.0f - dec) * d2[idx] + mn;
            d2[idx] = dn;
            W2eb[idx] = f2b(Wm2[idx] + dn);
        });
    }
}

// S6: hbb = bf16(silu(qt @ W1e^T))
__global__ __launch_bounds__(256) void s6_k(const ushort* __restrict__ qt,
                                            const ushort* __restrict__ W1eb,
                                            ushort* __restrict__ hbb) {
    __shared__ ushort As[64 * SA], Bs[64 * SA];
    f32x4 acc[2][2]; zacc(acc);
    const int m0 = blockIdx.y * 64, n0 = blockIdx.x * 64;
    gemm_core(qt, DD, false, W1eb, DD, false, DD, m0, n0, As, Bs, acc);
    epilogue(m0, n0, acc, [&](int row, int col, float val) {
        const float sg = sigmoidf_(val);
        hbb[(size_t)row * HH + col] = f2b(val * sg);
    });
}

// S7: ycall[t] = bf16(h @ W2e^T)
__global__ __launch_bounds__(256) void s7_k(const ushort* __restrict__ hbb,
                                            const ushort* __restrict__ W2eb,
                                            ushort* __restrict__ yc) {
    __shared__ ushort As[64 * SA], Bs[64 * SA];
    f32x4 acc[2][2]; zacc(acc);
    const int m0 = blockIdx.y * 64, n0 = blockIdx.x * 64;
    gemm_core(hbb, HH, false, W2eb, HH, false, HH, m0, n0, As, Bs, acc);
    epilogue(m0, n0, acc, [&](int row, int col, float val) {
        yc[(size_t)row * DD + col] = f2b(val);
    });
}

// Final: out = ycall @ Wout^T, scattered from chunk-major rows to [B,S,D]
__global__ __launch_bounds__(256) void out_k(const ushort* __restrict__ ycall,
                                             const ushort* __restrict__ Woutb,
                                             float* __restrict__ out) {
    __shared__ ushort As[64 * SA], Bs[64 * SA];
    f32x4 acc[2][2]; zacc(acc);
    const int m0 = blockIdx.y * 64, n0 = blockIdx.x * 64;
    gemm_core(ycall, DD, false, Woutb, DD, false, DD, m0, n0, As, Bs, acc);
    epilogue(m0, n0, acc, [&](int row, int col, float val) {
        const int t = row >> 8, b = (row >> 6) & 3, c = row & 63;
        out[((size_t)b * SS + (size_t)t * CHK + c) * DD + col] = val;
    });
}

// ---------------------------------------------------------------------------
extern "C" void kernel_launch(void* const* d_in, const int* in_sizes, int n_in,
                              void* d_out, int out_size, void* d_ws, size_t ws_size,
                              hipStream_t stream)
{
    const float* x    = (const float*)d_in[0];
    const float* Wk   = (const float*)d_in[1];
    const float* Wv   = (const float*)d_in[2];
    const float* Wq   = (const float*)d_in[3];
    const float* Wout = (const float*)d_in[4];
    const float* Wm1  = (const float*)d_in[5];
    const float* Wm2  = (const float*)d_in[6];
    const float* gdw  = (const float*)d_in[7];
    const float* gdb  = (const float*)d_in[8];
    const float* glw  = (const float*)d_in[9];
    const float* glb  = (const float*)d_in[10];
    const float* gmw  = (const float*)d_in[11];
    const float* gmb  = (const float*)d_in[12];
    float* out = (float*)d_out;

    char* w = (char*)d_ws;
    size_t off = 0;
    auto alloc = [&](size_t bytes) {
        off = (off + 255) & ~(size_t)255;
        char* p = w + off;
        off += bytes;
        return p;
    };

    const size_t M = (size_t)BB * SS;                 // 16384
    float*  kpre = (float*)alloc(M * DD * 4);         // f32 chunk-major; ycall aliases
    float*  qpre = (float*)alloc(M * DD * 4);
    ushort* xb   = (ushort*)alloc(M * DD * 2);        // ktb aliases after projections
    ushort* qtb  = (ushort*)alloc(M * DD * 2);
    ushort* vcb  = (ushort*)alloc(M * DD * 2);
    float*  d1   = (float*)alloc((size_t)HH * DD * 4);  // state: 4 contiguous blocks
    float*  d2   = (float*)alloc((size_t)HH * DD * 4);
    float*  m1   = (float*)alloc((size_t)HH * DD * 4);
    float*  m2   = (float*)alloc((size_t)HH * DD * 4);
    ushort* W1eb = (ushort*)alloc((size_t)HH * DD * 2);
    ushort* W2eb = (ushort*)alloc((size_t)HH * DD * 2);
    ushort* Wkb  = (ushort*)alloc((size_t)DD * DD * 2);
    ushort* Wvb  = (ushort*)alloc((size_t)DD * DD * 2);
    ushort* Wqb  = (ushort*)alloc((size_t)DD * DD * 2);
    ushort* Woutb= (ushort*)alloc((size_t)DD * DD * 2);
    ushort* a1b  = (ushort*)alloc((size_t)TOK * HH * 2);
    float*  ds1  = (float*)alloc((size_t)TOK * HH * 4);
    ushort* db1b = (ushort*)alloc((size_t)TOK * HH * 2);
    ushort* db2b = (ushort*)alloc((size_t)TOK * DD * 2);
    ushort* hbb  = (ushort*)alloc((size_t)TOK * HH * 2);
    float*  gtok = (float*)alloc((size_t)3 * NCHK * TOK * 4);
    float*  gates= (float*)alloc((size_t)3 * NCHK * 4);

    ushort* ktb   = xb;             // alias: xb dead after projection GEMMs
    ushort* ycall = (ushort*)kpre;  // alias: kpre dead after l2norm

    // zero scan state (d1,d2,m1,m2 contiguous)
    hipMemsetAsync(d1, 0, (size_t)4 * HH * DD * 4, stream);

    const dim3 blk(256);

    // bf16 conversions
    conv_k<<<dim3((M * DD / 4 + 255) / 256), blk, 0, stream>>>(x, xb, (int)(M * DD / 4));
    conv_k<<<dim3((DD * DD / 4 + 255) / 256), blk, 0, stream>>>(Wk, Wkb, DD * DD / 4);
    conv_k<<<dim3((DD * DD / 4 + 255) / 256), blk, 0, stream>>>(Wv, Wvb, DD * DD / 4);
    conv_k<<<dim3((DD * DD / 4 + 255) / 256), blk, 0, stream>>>(Wq, Wqb, DD * DD / 4);
    conv_k<<<dim3((DD * DD / 4 + 255) / 256), blk, 0, stream>>>(Wout, Woutb, DD * DD / 4);
    conv_k<<<dim3((HH * DD / 4 + 255) / 256), blk, 0, stream>>>(Wm1, W1eb, HH * DD / 4);
    conv_k<<<dim3((HH * DD / 4 + 255) / 256), blk, 0, stream>>>(Wm2, W2eb, HH * DD / 4);

    // projections (chunk-major epilogue)
    proj_k<0><<<dim3(DD / 64, M / 64), blk, 0, stream>>>(xb, Wkb, kpre, nullptr);
    proj_k<1><<<dim3(DD / 64, M / 64), blk, 0, stream>>>(xb, Wvb, nullptr, vcb);
    proj_k<0><<<dim3(DD / 64, M / 64), blk, 0, stream>>>(xb, Wqb, qpre, nullptr);

    // l2norm + bf16 (ktb aliases xb: safe, stream-ordered after projections)
    l2n_k<<<dim3(M / 4, 2), blk, 0, stream>>>(kpre, qpre, ktb, qtb);

    // gates
    gates_tok_k<<<dim3(M / 4), blk, 0, stream>>>(x, gdw, gdb, glw, glb, gmw, gmb, gtok);
    gates_red_k<<<dim3(NCHK), blk, 0, stream>>>(gtok, gates);

    for (int t = 0; t < NCHK; ++t) {
        const ushort* kt = ktb + (size_t)t * TOK * DD;
        const ushort* vt = vcb + (size_t)t * TOK * DD;
        const ushort* qt = qtb + (size_t)t * TOK * DD;

        s1_k<<<dim3(HH / 64, TOK / 64), blk, 0, stream>>>(kt, W1eb, a1b, ds1);
        s2_k<<<dim3(DD / 64, TOK / 64), blk, 0, stream>>>(a1b, W2eb, vt, db2b);
        s3_k<<<dim3(HH / 64, TOK / 64), blk, 0, stream>>>(db2b, W2eb, ds1, db1b);
        s45_k<<<dim3(256), blk, 0, stream>>>(db1b, kt, db2b, a1b,
                                             m1, d1, Wm1, W1eb,
                                             m2, d2, Wm2, W2eb, gates, t);
        s6_k<<<dim3(HH / 64, TOK / 64), blk, 0, stream>>>(qt, W1eb, hbb);
        s7_k<<<dim3(DD / 64, TOK / 64), blk, 0, stream>>>(hbb, W2eb,
                                                          ycall + (size_t)t * TOK * DD);
    }

    out_k<<<dim3(DD / 64, M / 64), blk, 0, stream>>>(ycall, Woutb, out);
}